// Round 5
// baseline (171.733 us; speedup 1.0000x reference)
//
#include <hip/hip_runtime.h>

#define THREADS 256
#define QPT 16
#define QP2 (QPT / 2)           // 8 float2 packs
#define SLICES 64
#define NPTS 8192
#define BATCH 4
#define SLICE (NPTS / SLICES)   // 128 targets per block
#define NMINS (2 * BATCH * NPTS)        // 65536
#define NBLOCKS ((NPTS / (THREADS * QPT)) * SLICES * 2 * BATCH)  // 2*64*8 = 1024

typedef float f2 __attribute__((ext_vector_type(2)));

// ws layout (all init 0xFF by one memset):
//   [0]        : uint ticket counter (starts 0xFFFFFFFF; k-th incrementer sees k-2)
//   [256 B ...]: mins[NMINS] uint  (0xFFFFFFFF > any positive-float bits = +inf)

__global__ __launch_bounds__(THREADS, 4) void chamfer_fused(
    const float* __restrict__ p1, const float* __restrict__ p2,
    unsigned int* __restrict__ wsu, float* __restrict__ out)
{
    unsigned int* ctr  = wsu;
    unsigned int* mins = wsu + 64;   // 256-byte offset

    const int tid  = threadIdx.x;
    const int dirb = blockIdx.z;         // 0..7 : dir*4 + batch
    const int dir  = dirb >> 2;
    const int b    = dirb & 3;
    const int qbase = blockIdx.x * (THREADS * QPT);
    const int tbase = blockIdx.y * SLICE;

    const float* __restrict__ qsrc = (dir == 0) ? p1 : p2;
    const float* __restrict__ tsrc = (dir == 0) ? p2 : p1;

    // ---- stage transformed targets into LDS: (-2x, -2y, -2z, |t|^2) ----
    __shared__ float4 tgt[SLICE];
    {
        const float* tp = tsrc + ((size_t)b * NPTS + tbase) * 3;
        for (int k = tid; k < SLICE; k += THREADS) {
            float x = tp[k * 3 + 0];
            float y = tp[k * 3 + 1];
            float z = tp[k * 3 + 2];
            tgt[k] = make_float4(-2.0f * x, -2.0f * y, -2.0f * z,
                                 fmaf(x, x, fmaf(y, y, z * z)));
        }
    }

    // ---- load this thread's queries, packed 2-wide ----
    f2 ax2[QP2], ay2[QP2], az2[QP2], best2[QP2];
#pragma unroll
    for (int j = 0; j < QP2; ++j) {
        const int qa = qbase + (2 * j + 0) * THREADS + tid;
        const int qb = qbase + (2 * j + 1) * THREADS + tid;
        const float* pa = qsrc + ((size_t)b * NPTS + qa) * 3;
        const float* pb = qsrc + ((size_t)b * NPTS + qb) * 3;
        ax2[j] = f2{pa[0], pb[0]};
        ay2[j] = f2{pa[1], pb[1]};
        az2[j] = f2{pa[2], pb[2]};
        best2[j] = f2{3.0e38f, 3.0e38f};
    }

    __syncthreads();

    // ---- main loop: 2 targets/iter, packed FMA (2 slots per 2 FLOPs), min3 ----
#pragma unroll 2
    for (int m = 0; m < SLICE; m += 2) {
        float4 ta = tgt[m];
        float4 tb = tgt[m + 1];
        f2 tax = {ta.x, ta.x}, tay = {ta.y, ta.y}, taz = {ta.z, ta.z}, taw = {ta.w, ta.w};
        f2 tbx = {tb.x, tb.x}, tby = {tb.y, tb.y}, tbz = {tb.z, tb.z}, tbw = {tb.w, tb.w};
#pragma unroll
        for (int j = 0; j < QP2; ++j) {
            f2 da = __builtin_elementwise_fma(ax2[j], tax,
                     __builtin_elementwise_fma(ay2[j], tay,
                      __builtin_elementwise_fma(az2[j], taz, taw)));
            f2 db = __builtin_elementwise_fma(ax2[j], tbx,
                     __builtin_elementwise_fma(ay2[j], tby,
                      __builtin_elementwise_fma(az2[j], tbz, tbw)));
            best2[j].x = fminf(fminf(best2[j].x, da.x), db.x);   // -> v_min3_f32
            best2[j].y = fminf(fminf(best2[j].y, da.y), db.y);
        }
    }

    // ---- epilogue: recompute |q|^2 (saves 16 live regs), clamp, atomicMin ----
    unsigned int* mbase = mins + ((size_t)dirb * NPTS);
#pragma unroll
    for (int j = 0; j < QP2; ++j) {
        f2 a2;
        a2.x = fmaf(ax2[j].x, ax2[j].x, fmaf(ay2[j].x, ay2[j].x, az2[j].x * az2[j].x));
        a2.y = fmaf(ax2[j].y, ax2[j].y, fmaf(ay2[j].y, ay2[j].y, az2[j].y * az2[j].y));
        float va = fmaxf(best2[j].x + a2.x, 0.0f);
        float vb = fmaxf(best2[j].y + a2.y, 0.0f);
        atomicMin(&mbase[qbase + (2 * j + 0) * THREADS + tid], __float_as_uint(va));
        atomicMin(&mbase[qbase + (2 * j + 1) * THREADS + tid], __float_as_uint(vb));
    }

    // ---- last-block-done reduction (device-scope atomics, per G16) ----
    __threadfence();                 // drain this thread's atomics (vmcnt) + release
    __syncthreads();                 // all threads in block have fenced
    __shared__ int is_last;
    if (tid == 0) {
        unsigned int old = atomicAdd(ctr, 1u);
        is_last = (old == (unsigned int)(NBLOCKS - 2));  // ctr starts at 0xFFFFFFFF
    }
    __syncthreads();
    if (!is_last) return;
    __threadfence();                 // acquire side

    // sum all 65536 mins; reads via non-modifying atomicMin -> coherent by path
    float s0 = 0.f, s1 = 0.f, s2 = 0.f, s3 = 0.f;
#pragma unroll 4
    for (int k = 0; k < NMINS / THREADS; k += 4) {   // 256 iters total, 4-wide
        unsigned int v0 = atomicMin(&mins[(k + 0) * THREADS + tid], 0xFFFFFFFFu);
        unsigned int v1 = atomicMin(&mins[(k + 1) * THREADS + tid], 0xFFFFFFFFu);
        unsigned int v2 = atomicMin(&mins[(k + 2) * THREADS + tid], 0xFFFFFFFFu);
        unsigned int v3 = atomicMin(&mins[(k + 3) * THREADS + tid], 0xFFFFFFFFu);
        s0 += __uint_as_float(v0);
        s1 += __uint_as_float(v1);
        s2 += __uint_as_float(v2);
        s3 += __uint_as_float(v3);
    }
    float s = (s0 + s1) + (s2 + s3);
#pragma unroll
    for (int off = 32; off >= 1; off >>= 1)
        s += __shfl_down(s, off, 64);
    __shared__ float partial[THREADS / 64];
    if ((tid & 63) == 0) partial[tid >> 6] = s;
    __syncthreads();
    if (tid == 0) {
        float tot = 0.0f;
#pragma unroll
        for (int w = 0; w < THREADS / 64; ++w) tot += partial[w];
        out[0] = tot * (1.0f / (BATCH * NPTS));
    }
}

extern "C" void kernel_launch(void* const* d_in, const int* in_sizes, int n_in,
                              void* d_out, int out_size, void* d_ws, size_t ws_size,
                              hipStream_t stream) {
    const float* p1 = (const float*)d_in[0];
    const float* p2 = (const float*)d_in[1];
    float* out = (float*)d_out;

    // one memset inits BOTH the ticket counter (0xFFFFFFFF) and mins (+inf bits)
    hipMemsetAsync(d_ws, 0xFF, 256 + (size_t)NMINS * 4, stream);

    // x = query blocks (2), y = target slices (64), z = dir*4+batch (8) -> 1024 blocks
    dim3 grid(NPTS / (THREADS * QPT), SLICES, 2 * BATCH);
    chamfer_fused<<<grid, THREADS, 0, stream>>>(p1, p2, (unsigned int*)d_ws, out);
}

// Round 6
// 106.414 us; speedup vs baseline: 1.6138x; 1.6138x over previous
//
#include <hip/hip_runtime.h>

#define THREADS 256
#define QPT 16
#define QP2 (QPT / 2)           // 8 float2 packs
#define SLICES 32
#define NPTS 8192
#define BATCH 4
#define SLICE (NPTS / SLICES)   // 256 targets per block

typedef float f2 __attribute__((ext_vector_type(2)));

// ws layout: partials [SLICES][2*BATCH][NPTS] float = 32*8*8192*4 = 8 MB (fit proven R4)

__global__ __launch_bounds__(THREADS) void chamfer_main(
    const float* __restrict__ p1, const float* __restrict__ p2,
    float* __restrict__ partials)
{
    const int tid  = threadIdx.x;
    const int dirb = blockIdx.z;         // 0..7 : dir*4 + batch
    const int dir  = dirb >> 2;
    const int b    = dirb & 3;
    const int qbase = blockIdx.x * (THREADS * QPT);
    const int tbase = blockIdx.y * SLICE;

    const float* __restrict__ qsrc = (dir == 0) ? p1 : p2;
    const float* __restrict__ tsrc = (dir == 0) ? p2 : p1;

    // ---- stage transformed targets into LDS: (-2x, -2y, -2z, |t|^2) ----
    __shared__ float4 tgt[SLICE];
    {
        const float* tp = tsrc + ((size_t)b * NPTS + tbase) * 3;
        for (int k = tid; k < SLICE; k += THREADS) {
            float x = tp[k * 3 + 0];
            float y = tp[k * 3 + 1];
            float z = tp[k * 3 + 2];
            tgt[k] = make_float4(-2.0f * x, -2.0f * y, -2.0f * z,
                                 fmaf(x, x, fmaf(y, y, z * z)));
        }
    }

    // ---- load this thread's queries, packed 2-wide ----
    f2 ax2[QP2], ay2[QP2], az2[QP2], best2[QP2];
#pragma unroll
    for (int j = 0; j < QP2; ++j) {
        const int qa = qbase + (2 * j + 0) * THREADS + tid;
        const int qb = qbase + (2 * j + 1) * THREADS + tid;
        const float* pa = qsrc + ((size_t)b * NPTS + qa) * 3;
        const float* pb = qsrc + ((size_t)b * NPTS + qb) * 3;
        ax2[j] = f2{pa[0], pb[0]};
        ay2[j] = f2{pa[1], pb[1]};
        az2[j] = f2{pa[2], pb[2]};
        best2[j] = f2{3.0e38f, 3.0e38f};
    }

    __syncthreads();

    // ---- main loop: 2 targets/iter, packed FMA (2.0 slots/pair), min3 fold ----
#pragma unroll 2
    for (int m = 0; m < SLICE; m += 2) {
        float4 ta = tgt[m];
        float4 tb = tgt[m + 1];
        f2 tax = {ta.x, ta.x}, tay = {ta.y, ta.y}, taz = {ta.z, ta.z}, taw = {ta.w, ta.w};
        f2 tbx = {tb.x, tb.x}, tby = {tb.y, tb.y}, tbz = {tb.z, tb.z}, tbw = {tb.w, tb.w};
#pragma unroll
        for (int j = 0; j < QP2; ++j) {
            f2 da = __builtin_elementwise_fma(ax2[j], tax,
                     __builtin_elementwise_fma(ay2[j], tay,
                      __builtin_elementwise_fma(az2[j], taz, taw)));
            f2 db = __builtin_elementwise_fma(ax2[j], tbx,
                     __builtin_elementwise_fma(ay2[j], tby,
                      __builtin_elementwise_fma(az2[j], tbz, tbw)));
            best2[j].x = fminf(fminf(best2[j].x, da.x), db.x);   // -> v_min3_f32
            best2[j].y = fminf(fminf(best2[j].y, da.y), db.y);
        }
    }

    // ---- epilogue: + |q|^2 (recomputed), clamp, plain coalesced stores ----
    float* pbase = partials + (((size_t)blockIdx.y * 8 + dirb) * NPTS);
#pragma unroll
    for (int j = 0; j < QP2; ++j) {
        f2 a2;
        a2.x = fmaf(ax2[j].x, ax2[j].x, fmaf(ay2[j].x, ay2[j].x, az2[j].x * az2[j].x));
        a2.y = fmaf(ax2[j].y, ax2[j].y, fmaf(ay2[j].y, ay2[j].y, az2[j].y * az2[j].y));
        float va = fmaxf(best2[j].x + a2.x, 0.0f);
        float vb = fmaxf(best2[j].y + a2.y, 0.0f);
        pbase[qbase + (2 * j + 0) * THREADS + tid] = va;
        pbase[qbase + (2 * j + 1) * THREADS + tid] = vb;
    }
}

// 65536 threads: each min-folds its (dirb,q) over 32 slices, then block-sum + atomicAdd
__global__ __launch_bounds__(THREADS) void chamfer_reduce_partials(
    const float* __restrict__ partials, float* __restrict__ out)
{
    const int i = blockIdx.x * THREADS + threadIdx.x;   // [0, 65536)
    const int dirb = i >> 13;
    const int q = i & (NPTS - 1);
    float v = 3.4e38f;
#pragma unroll 8
    for (int s = 0; s < SLICES; ++s)
        v = fminf(v, partials[((size_t)s * 8 + dirb) * NPTS + q]);

    float sv = v;
#pragma unroll
    for (int off = 32; off >= 1; off >>= 1)
        sv += __shfl_down(sv, off, 64);
    __shared__ float partial[THREADS / 64];
    if ((threadIdx.x & 63) == 0) partial[threadIdx.x >> 6] = sv;
    __syncthreads();
    if (threadIdx.x == 0) {
        float tot = 0.0f;
#pragma unroll
        for (int w = 0; w < THREADS / 64; ++w) tot += partial[w];
        atomicAdd(out, tot * (1.0f / (BATCH * NPTS)));
    }
}

extern "C" void kernel_launch(void* const* d_in, const int* in_sizes, int n_in,
                              void* d_out, int out_size, void* d_ws, size_t ws_size,
                              hipStream_t stream) {
    const float* p1 = (const float*)d_in[0];
    const float* p2 = (const float*)d_in[1];
    float* out = (float*)d_out;

    hipMemsetAsync(d_out, 0, sizeof(float), stream);

    // x = query blocks (8192/4096=2), y = slices (32), z = dir*4+batch (8) -> 512 blocks
    dim3 grid(NPTS / (THREADS * QPT), SLICES, 2 * BATCH);
    chamfer_main<<<grid, THREADS, 0, stream>>>(p1, p2, (float*)d_ws);

    chamfer_reduce_partials<<<(2 * BATCH * NPTS) / THREADS, THREADS, 0, stream>>>(
        (const float*)d_ws, out);
}